// Round 13
// baseline (323.512 us; speedup 1.0000x reference)
//
#include <hip/hip_runtime.h>
#include <hip/hip_bf16.h>

#define N_    2048
#define FIN   256
#define FOUT  128
#define ALPHA 0.01f

typedef short bf16x8 __attribute__((ext_vector_type(8)));
typedef float f32x4  __attribute__((ext_vector_type(4)));

static __device__ __forceinline__ unsigned short f2bf(float x) {
    __hip_bfloat16 h = __float2bfloat16(x);
    return *reinterpret_cast<unsigned short*>(&h);
}
static __device__ __forceinline__ float bf2f(unsigned short u) {
    return __uint_as_float(((unsigned)u) << 16);
}

// ---------------------------------------------------------------------------
// W split -> fragment-major bf16 hi/lo (unchanged, verified R6)
__global__ __launch_bounds__(256) void k_wsplit(
    const float* __restrict__ W, unsigned short* __restrict__ WFhi,
    unsigned short* __restrict__ WFlo)
{
    int idx = blockIdx.x * 256 + threadIdx.x;
    int k = idx >> 7, n = idx & 127;
    float w = W[k * 128 + n];
    unsigned short hi = f2bf(w);
    unsigned short lo = f2bf(w - bf2f(hi));
    int nb = n >> 4, ln = n & 15, ks = k >> 5, lg = (k >> 3) & 3, e = k & 7;
    int off = (((nb * 8 + ks) * 4 + lg) * 16 + ln) * 8 + e;
    WFhi[off] = hi;
    WFlo[off] = lo;
}

// ---------------------------------------------------------------------------
// adj pack v3: 2048 blocks x 8 rows. byte (row, lg, S) = bits of
// adj[row][S*32 + lg*8 .. +7], stored at mask[row*256 + lg*64 + S]
// (R9-verified layout). One barrier; coalesced 2KB store per block.
__global__ __launch_bounds__(256) void k_pack(
    const int* __restrict__ adj, unsigned char* __restrict__ mask)
{
    __shared__ unsigned char mb[8 * 256];
    int g = blockIdx.x;                         // 2048
    size_t row0 = (size_t)g * 8;
    int t = threadIdx.x;
    int S = t >> 2, lg = t & 3;                 // j = t*8 = S*32 + lg*8

#pragma unroll
    for (int rr = 0; rr < 8; ++rr) {
        const int4* a4 = reinterpret_cast<const int4*>(adj + (row0 + rr) * N_) + 2 * t;
        int4 x = a4[0], y = a4[1];
        unsigned byte =
            (unsigned)(x.x > 0) | ((unsigned)(x.y > 0) << 1) |
            ((unsigned)(x.z > 0) << 2) | ((unsigned)(x.w > 0) << 3) |
            ((unsigned)(y.x > 0) << 4) | ((unsigned)(y.y > 0) << 5) |
            ((unsigned)(y.z > 0) << 6) | ((unsigned)(y.w > 0) << 7);
        mb[rr * 256 + lg * 64 + S] = (unsigned char)byte;
    }
    __syncthreads();
    if (t < 128)
        reinterpret_cast<uint4*>(mask + row0 * 256)[t] =
            reinterpret_cast<const uint4*>(mb)[t];
}

// ---------------------------------------------------------------------------
// h = inp @ W via 3-term split-bf16 MFMA (unchanged, verified R6/R10)
__global__ __launch_bounds__(256) void k_lin(
    const float* __restrict__ inp,
    const unsigned short* __restrict__ WFhi, const unsigned short* __restrict__ WFlo,
    const float* __restrict__ av, unsigned short* __restrict__ hF,
    float* __restrict__ s1, float* __restrict__ s2)
{
    __shared__ unsigned short Ahi[64 * 256];
    __shared__ unsigned short Alo[64 * 256];

    int g = blockIdx.x;            // 256 blocks
    int b = g & 7;
    int i0 = (g >> 3) << 6;
    int t = threadIdx.x;

    {
        int row = t >> 2;
        const float* src = inp + ((size_t)(b * N_ + i0 + row)) * FIN + (t & 3) * 64;
#pragma unroll
        for (int gseg = 0; gseg < 8; ++gseg) {
            float4 f0 = *reinterpret_cast<const float4*>(src + gseg * 8);
            float4 f1 = *reinterpret_cast<const float4*>(src + gseg * 8 + 4);
            float f[8] = {f0.x, f0.y, f0.z, f0.w, f1.x, f1.y, f1.z, f1.w};
            bf16x8 hi8, lo8;
#pragma unroll
            for (int e = 0; e < 8; ++e) {
                unsigned short h = f2bf(f[e]);
                hi8[e] = (short)h;
                lo8[e] = (short)f2bf(f[e] - bf2f(h));
            }
            int k = (t & 3) * 64 + gseg * 8;
            int off = (row * 512 + k * 2) ^ ((row & 7) << 4);
            *reinterpret_cast<bf16x8*>(reinterpret_cast<char*>(Ahi) + off) = hi8;
            *reinterpret_cast<bf16x8*>(reinterpret_cast<char*>(Alo) + off) = lo8;
        }
    }
    __syncthreads();

    int w = t >> 6, l = t & 63;
    int ln = l & 15, lg = l >> 4;
    const bf16x8* Wh8 = reinterpret_cast<const bf16x8*>(WFhi);
    const bf16x8* Wl8 = reinterpret_cast<const bf16x8*>(WFlo);

    f32x4 acc[8];
#pragma unroll
    for (int nb = 0; nb < 8; ++nb) acc[nb] = (f32x4){0.f, 0.f, 0.f, 0.f};

#pragma unroll
    for (int ks = 0; ks < 8; ++ks) {
        int arow = w * 16 + ln;
        int aoff = (arow * 512 + ks * 64 + lg * 16) ^ ((arow & 7) << 4);
        bf16x8 ahi = *reinterpret_cast<const bf16x8*>(reinterpret_cast<const char*>(Ahi) + aoff);
        bf16x8 alo = *reinterpret_cast<const bf16x8*>(reinterpret_cast<const char*>(Alo) + aoff);
#pragma unroll
        for (int nb = 0; nb < 8; ++nb) {
            int fi = ((nb * 8 + ks) * 4 + lg) * 16 + ln;
            bf16x8 whi = Wh8[fi];
            bf16x8 wlo = Wl8[fi];
            acc[nb] = __builtin_amdgcn_mfma_f32_16x16x32_bf16(ahi, whi, acc[nb], 0, 0, 0);
            acc[nb] = __builtin_amdgcn_mfma_f32_16x16x32_bf16(alo, whi, acc[nb], 0, 0, 0);
            acc[nb] = __builtin_amdgcn_mfma_f32_16x16x32_bf16(ahi, wlo, acc[nb], 0, 0, 0);
        }
    }

    float p1[4] = {0.f, 0.f, 0.f, 0.f}, p2[4] = {0.f, 0.f, 0.f, 0.f};
#pragma unroll
    for (int nb = 0; nb < 8; ++nb) {
        float a1 = av[nb * 16 + ln];
        float a2 = av[FOUT + nb * 16 + ln];
#pragma unroll
        for (int j = 0; j < 4; ++j) {
            p1[j] = fmaf(acc[nb][j], a1, p1[j]);
            p2[j] = fmaf(acc[nb][j], a2, p2[j]);
        }
    }
#pragma unroll
    for (int off = 1; off < 16; off <<= 1)
#pragma unroll
        for (int j = 0; j < 4; ++j) {
            p1[j] += __shfl_xor(p1[j], off);
            p2[j] += __shfl_xor(p2[j], off);
        }
    if (ln == 0) {
#pragma unroll
        for (int j = 0; j < 4; ++j) {
            int row = i0 + w * 16 + lg * 4 + j;
            s1[b * N_ + row] = p1[j];
            s2[b * N_ + row] = p2[j];
        }
    }

    __syncthreads();
    unsigned short* T = Ahi;
#pragma unroll
    for (int nb = 0; nb < 8; ++nb)
#pragma unroll
        for (int j = 0; j < 4; ++j)
            T[(nb * 16 + ln) * 68 + w * 16 + lg * 4 + j] = f2bf(acc[nb][j]);
    __syncthreads();
    {
        int f = t & 127, half = t >> 7;
        int J = (i0 >> 5) + half;
        unsigned short tmp[32];
#pragma unroll
        for (int c = 0; c < 32; ++c) tmp[c] = T[f * 68 + half * 32 + c];
        int4* dst = reinterpret_cast<int4*>(&hF[(((size_t)(b * 64 + J)) * 128 + f) * 32]);
#pragma unroll
        for (int c = 0; c < 4; ++c) dst[c] = reinterpret_cast<const int4*>(tmp)[c];
    }
}

// ---------------------------------------------------------------------------
// k_attn v7: 64 rows/block (256 blocks), 4 waves x 16 rows, FULL-j sweep per
// wave -> all waves read the SAME fragment stream (L1/L2-served, hF[b]
// L2-resident via b=g&7 XCD pinning). No accb, no cross-wave merge, zero
// barriers in main loop. LDS = s2 only (8.3 KB). Mask-based, no-shift softmax.
__global__ __launch_bounds__(256, 2) void k_attn(
    const unsigned char* __restrict__ mask, const unsigned short* __restrict__ hF,
    const float* __restrict__ s1g, const float* __restrict__ s2g,
    float* __restrict__ out)
{
    __shared__ float s2_lds[N_];         // 8 KB

    int g = blockIdx.x;                  // 256
    int b = g & 7;                       // XCD-affine
    int i0 = (g >> 3) << 6;              // 64 rows
    int t = threadIdx.x;
    int w = t >> 6, l = t & 63;
    int r = l & 15, lg = l >> 4;

    {
        const float4* s2g4 = reinterpret_cast<const float4*>(s2g + b * N_);
        reinterpret_cast<float4*>(s2_lds)[t] = s2g4[t];
        reinterpret_cast<float4*>(s2_lds)[t + 256] = s2g4[t + 256];
    }

    const int myrow = i0 + w * 16 + r;
    const float s1r = s1g[b * N_ + myrow];

    // mask bytes for (row, lg): [row*256 + lg*64 + S], uint4 per 16 steps
    const unsigned char* mrow = mask + ((size_t)(b * N_ + myrow)) * 256 + lg * 64;

    // frag (S,q): hF[((b*64 + S)*128 + q*16 + r)*32 + lg*8 ..]
    const bf16x8* hv = reinterpret_cast<const bf16x8*>(hF)
        + (((size_t)(b * 64) * 128 + r) * 4 + lg);
    // S stride 512, q stride 64 (bf16x8 units)

    float l_run = 0.f;
    f32x4 acc[8];
#pragma unroll
    for (int q = 0; q < 8; ++q) acc[q] = (f32x4){0.f, 0.f, 0.f, 0.f};

    // prologue: frag S=0 + mask u=0 in flight before the s2 barrier
    bf16x8 hA[8], hB[8];
#pragma unroll
    for (int q = 0; q < 8; ++q) hA[q] = hv[q * 64];
    uint4 mv_cur = *reinterpret_cast<const uint4*>(mrow);

    __syncthreads();   // s2_lds ready

    for (int u = 0; u < 4; ++u) {
        uint4 mv_next = *reinterpret_cast<const uint4*>(mrow + (u < 3 ? (u + 1) * 16 : 48));
#pragma unroll
        for (int s = 0; s < 16; ++s) {
            const int S = u * 16 + s;
            auto& cur = (S & 1) ? hB : hA;
            auto& nxt = (S & 1) ? hA : hB;
            const int Sn = (S < 63) ? S + 1 : 63;
#pragma unroll
            for (int q = 0; q < 8; ++q) nxt[q] = hv[(size_t)Sn * 512 + q * 64];

            unsigned byte = ((&mv_cur.x)[s >> 2] >> ((s & 3) * 8)) & 0xffu;
            const float* s2b = &s2_lds[S * 32 + lg * 8];
            float4 ca = *reinterpret_cast<const float4*>(s2b);
            float4 cb = *reinterpret_cast<const float4*>(s2b + 4);
            float sv[8] = {ca.x, ca.y, ca.z, ca.w, cb.x, cb.y, cb.z, cb.w};

            bf16x8 af;
            float ps = 0.f;
#pragma unroll
            for (int e = 0; e < 8; ++e) {
                float v = s1r + sv[e];
                v = fmaxf(v, ALPHA * v);
                float p = (byte & (1u << e)) ? __expf(v) : 0.f;   // no shift
                ps += p;
                af[e] = (short)f2bf(p);
            }
            l_run += ps;
#pragma unroll
            for (int q = 0; q < 8; ++q)
                acc[q] = __builtin_amdgcn_mfma_f32_16x16x32_bf16(af, cur[q], acc[q], 0, 0, 0);
        }
        mv_cur = mv_next;
    }

    // wave-local epilogue (R9-verified pattern)
    l_run += __shfl_xor(l_run, 16);
    l_run += __shfl_xor(l_run, 32);
    float Lr[4];
#pragma unroll
    for (int rr = 0; rr < 4; ++rr)
        Lr[rr] = __shfl(l_run, lg * 4 + rr);

    float* ob = out + ((size_t)(b * N_ + i0 + w * 16)) * FOUT;
#pragma unroll
    for (int q = 0; q < 8; ++q)
#pragma unroll
        for (int rr = 0; rr < 4; ++rr) {
            float v = acc[q][rr] / Lr[rr];
            ob[(size_t)(lg * 4 + rr) * FOUT + q * 16 + r] = fmaxf(v, 0.f);
        }
}

extern "C" void kernel_launch(void* const* d_in, const int* in_sizes, int n_in,
                              void* d_out, int out_size, void* d_ws, size_t ws_size,
                              hipStream_t stream) {
    (void)in_sizes; (void)n_in; (void)out_size; (void)ws_size;
    const float* inp = (const float*)d_in[0];
    const int*   adj = (const int*)d_in[1];
    const float* W   = (const float*)d_in[2];
    const float* a   = (const float*)d_in[3];
    float* out = (float*)d_out;

    char* ws = (char*)d_ws;
    unsigned short* hF   = (unsigned short*)ws;                         // 4 MB
    unsigned char*  mask = (unsigned char*)(ws + (4u << 20));           // 4 MB
    float* s1    = (float*)(ws + (8u << 20));                           // 64 KB
    float* s2    = s1 + 8 * N_;                                         // 64 KB
    unsigned short* WFhi = (unsigned short*)(s2 + 8 * N_);              // 64 KB
    unsigned short* WFlo = WFhi + FIN * FOUT;                           // 64 KB

    k_wsplit<<<128, 256, 0, stream>>>(W, WFhi, WFlo);
    k_pack<<<2048, 256, 0, stream>>>(adj, mask);
    k_lin<<<256, 256, 0, stream>>>(inp, WFhi, WFlo, a, hF, s1, s2);
    k_attn<<<256, 256, 0, stream>>>(mask, hF, s1, s2, out);
}